// Round 2
// baseline (450.219 us; speedup 1.0000x reference)
//
#include <hip/hip_runtime.h>
#include <math.h>

#define PCEN_EPS 1e-6f

// x is [B, T, M] fp32 with M = 80 = 4*Q, Q = 20. All rows 320B-aligned, so
// float4 loads per lane (16 B) are aligned and coalesced. Each thread owns
// 4 adjacent mel channels of one (batch, chunk). EMA chains are independent
// per channel; loads are address-independent of the chain, so unroll 8 keeps
// 8 x 16 B in flight per lane.

// ---------------------------------------------------------------------------
// K1: per-(b, chunk, q) local EMA scan from m=0 -> chunk contribution.
// ---------------------------------------------------------------------------
__global__ void pcen_chunk_scan(const float4* __restrict__ x,
                                const float* __restrict__ log_s,
                                float4* __restrict__ contrib,
                                int B, int T, int Q, int C, int L) {
    int tid = blockIdx.x * blockDim.x + threadIdx.x;
    int total = B * C * Q;
    if (tid >= total) return;
    int q = tid % Q;
    int c = (tid / Q) % C;
    int b = tid / (Q * C);

    float sx = expf(log_s[q * 4 + 0]);
    float sy = expf(log_s[q * 4 + 1]);
    float sz = expf(log_s[q * 4 + 2]);
    float sw = expf(log_s[q * 4 + 3]);
    float ox = 1.0f - sx, oy = 1.0f - sy, oz = 1.0f - sz, ow = 1.0f - sw;

    int start = c * L;
    int len = T - start;
    if (len > L) len = L;
    if (len < 0) len = 0;

    long base = (long)(b * (long)T + start) * Q + q;
    float mx = 0.f, my = 0.f, mz = 0.f, mw = 0.f;
#pragma unroll 8
    for (int i = 0; i < len; ++i) {
        float4 xv = x[base];
        mx = fmaf(ox, mx, sx * xv.x);
        my = fmaf(oy, my, sy * xv.y);
        mz = fmaf(oz, mz, sz * xv.z);
        mw = fmaf(ow, mw, sw * xv.w);
        base += Q;
    }
    contrib[tid] = make_float4(mx, my, mz, mw);  // layout [b][c][q]
}

// ---------------------------------------------------------------------------
// K2: per-(b, q) serial prefix across the C chunks (tiny).
// m_start[c] = state entering chunk c; m_end = (1-s)^len * m_start + contrib.
// ---------------------------------------------------------------------------
__global__ void pcen_chunk_prefix(const float4* __restrict__ contrib,
                                  const float* __restrict__ log_s,
                                  float4* __restrict__ m_start,
                                  int B, int T, int Q, int C, int L) {
    int tid = blockIdx.x * blockDim.x + threadIdx.x;
    if (tid >= B * Q) return;
    int q = tid % Q;
    int b = tid / Q;

    float sx = expf(log_s[q * 4 + 0]);
    float sy = expf(log_s[q * 4 + 1]);
    float sz = expf(log_s[q * 4 + 2]);
    float sw = expf(log_s[q * 4 + 3]);
    float ox = 1.0f - sx, oy = 1.0f - sy, oz = 1.0f - sz, ow = 1.0f - sw;

    float mx = 0.f, my = 0.f, mz = 0.f, mw = 0.f;
    int base = b * C * Q + q;
    for (int c = 0; c < C; ++c) {
        m_start[base + c * Q] = make_float4(mx, my, mz, mw);
        int start = c * L;
        int len = T - start;
        if (len > L) len = L;
        if (len < 0) len = 0;
        float dx = powf(ox, (float)len);
        float dy = powf(oy, (float)len);
        float dz = powf(oz, (float)len);
        float dw = powf(ow, (float)len);
        float4 cv = contrib[base + c * Q];
        mx = fmaf(dx, mx, cv.x);
        my = fmaf(dy, my, cv.y);
        mz = fmaf(dz, mz, cv.z);
        mw = fmaf(dw, mw, cv.w);
    }
}

// ---------------------------------------------------------------------------
// K3: per-(b, chunk, q) re-scan with correct start state + PCEN epilogue.
// out = (x * (m+eps)^-alpha + delta)^r - delta^r
// ---------------------------------------------------------------------------
__device__ __forceinline__ float pcen_out(float xv, float m, float alpha,
                                          float delta, float r, float delta_r) {
    float p = __expf(-alpha * __logf(m + PCEN_EPS));
    float y = fmaf(xv, p, delta);
    return __expf(r * __logf(y)) - delta_r;
}

__global__ void pcen_output(const float4* __restrict__ x,
                            const float* __restrict__ log_s,
                            const float* __restrict__ log_alpha,
                            const float* __restrict__ log_delta,
                            const float* __restrict__ log_r,
                            const float4* __restrict__ m_start,
                            float4* __restrict__ out,
                            int B, int T, int Q, int C, int L) {
    int tid = blockIdx.x * blockDim.x + threadIdx.x;
    int total = B * C * Q;
    if (tid >= total) return;
    int q = tid % Q;
    int c = (tid / Q) % C;
    int b = tid / (Q * C);

    float sx = expf(log_s[q * 4 + 0]);
    float sy = expf(log_s[q * 4 + 1]);
    float sz = expf(log_s[q * 4 + 2]);
    float sw = expf(log_s[q * 4 + 3]);
    float ox = 1.0f - sx, oy = 1.0f - sy, oz = 1.0f - sz, ow = 1.0f - sw;

    float ax = expf(log_alpha[q * 4 + 0]);
    float ay = expf(log_alpha[q * 4 + 1]);
    float az = expf(log_alpha[q * 4 + 2]);
    float aw = expf(log_alpha[q * 4 + 3]);

    float dx = expf(log_delta[q * 4 + 0]);
    float dy = expf(log_delta[q * 4 + 1]);
    float dz = expf(log_delta[q * 4 + 2]);
    float dw = expf(log_delta[q * 4 + 3]);

    float rx = expf(log_r[q * 4 + 0]);
    float ry = expf(log_r[q * 4 + 1]);
    float rz = expf(log_r[q * 4 + 2]);
    float rw = expf(log_r[q * 4 + 3]);

    float drx = powf(dx, rx), dry = powf(dy, ry);
    float drz = powf(dz, rz), drw = powf(dw, rw);

    int start = c * L;
    int len = T - start;
    if (len > L) len = L;
    if (len < 0) len = 0;

    float4 m0 = m_start[tid];
    float mx = m0.x, my = m0.y, mz = m0.z, mw = m0.w;

    long base = (long)(b * (long)T + start) * Q + q;
#pragma unroll 8
    for (int i = 0; i < len; ++i) {
        float4 xv = x[base];
        mx = fmaf(ox, mx, sx * xv.x);
        my = fmaf(oy, my, sy * xv.y);
        mz = fmaf(oz, mz, sz * xv.z);
        mw = fmaf(ow, mw, sw * xv.w);
        float4 ov;
        ov.x = pcen_out(xv.x, mx, ax, dx, rx, drx);
        ov.y = pcen_out(xv.y, my, ay, dy, ry, dry);
        ov.z = pcen_out(xv.z, mz, az, dz, rz, drz);
        ov.w = pcen_out(xv.w, mw, aw, dw, rw, drw);
        out[base] = ov;
        base += Q;
    }
}

extern "C" void kernel_launch(void* const* d_in, const int* in_sizes, int n_in,
                              void* d_out, int out_size, void* d_ws, size_t ws_size,
                              hipStream_t stream) {
    const float4* x        = (const float4*)d_in[0];
    const float* log_s     = (const float*)d_in[1];
    const float* log_alpha = (const float*)d_in[2];
    const float* log_delta = (const float*)d_in[3];
    const float* log_r     = (const float*)d_in[4];
    float4* out = (float4*)d_out;

    const int M = in_sizes[1];            // 80
    const int Q = M / 4;                  // 20 float4s per row
    const int B = 64;                     // per reference setup
    const int T = in_sizes[0] / (B * M);  // 8000

    // Chunk count C: parallelism = B*C*Q threads; workspace = 2*B*C*M floats.
    int C = 100;
    while (C > 1 && (size_t)(2ll * B * C * M * 4) > ws_size) C--;
    const int L = (T + C - 1) / C;

    float4* contrib = (float4*)d_ws;                       // B*C*Q float4s
    float4* mstart  = contrib + (size_t)B * C * Q;         // B*C*Q float4s

    const int threads = 256;
    int total1 = B * C * Q;
    int total2 = B * Q;

    pcen_chunk_scan<<<(total1 + threads - 1) / threads, threads, 0, stream>>>(
        x, log_s, contrib, B, T, Q, C, L);
    pcen_chunk_prefix<<<(total2 + threads - 1) / threads, threads, 0, stream>>>(
        contrib, log_s, mstart, B, T, Q, C, L);
    pcen_output<<<(total1 + threads - 1) / threads, threads, 0, stream>>>(
        x, log_s, log_alpha, log_delta, log_r, mstart, out, B, T, Q, C, L);
}

// Round 4
// 382.660 us; speedup vs baseline: 1.1766x; 1.1766x over previous
//
#include <hip/hip_runtime.h>
#include <math.h>

#define PCEN_EPS 1e-6f

// native clang vector type: __builtin_nontemporal_store accepts this
// (it rejects HIP's class-type float4).
typedef float vfloat4 __attribute__((ext_vector_type(4)));

// x is [B, T, M] fp32 with M = 80 = 4*Q, Q = 20. Rows are 320B-aligned, so
// float4 loads per lane are aligned and coalesced. Each thread owns 4
// adjacent mel channels of one (batch, chunk); time is the serial dim.

// ---------------------------------------------------------------------------
// K1: per-(b, chunk, q) local EMA scan from m=0 -> chunk contribution.
// ---------------------------------------------------------------------------
__global__ void pcen_chunk_scan(const float4* __restrict__ x,
                                const float* __restrict__ log_s,
                                float4* __restrict__ contrib,
                                int B, int T, int Q, int C, int L) {
    int tid = blockIdx.x * blockDim.x + threadIdx.x;
    int total = B * C * Q;
    if (tid >= total) return;
    int q = tid % Q;
    int c = (tid / Q) % C;
    int b = tid / (Q * C);

    float sx = expf(log_s[q * 4 + 0]);
    float sy = expf(log_s[q * 4 + 1]);
    float sz = expf(log_s[q * 4 + 2]);
    float sw = expf(log_s[q * 4 + 3]);
    float ox = 1.0f - sx, oy = 1.0f - sy, oz = 1.0f - sz, ow = 1.0f - sw;

    int start = c * L;
    int len = T - start;
    if (len > L) len = L;
    if (len < 0) len = 0;

    long base = (long)(b * (long)T + start) * Q + q;
    float mx = 0.f, my = 0.f, mz = 0.f, mw = 0.f;
#pragma unroll 8
    for (int i = 0; i < len; ++i) {
        float4 xv = x[base];
        mx = fmaf(ox, mx, sx * xv.x);
        my = fmaf(oy, my, sy * xv.y);
        mz = fmaf(oz, mz, sz * xv.z);
        mw = fmaf(ow, mw, sw * xv.w);
        base += Q;
    }
    contrib[tid] = make_float4(mx, my, mz, mw);  // layout [b][c][q]
}

// ---------------------------------------------------------------------------
// K2: per-(b, q) serial prefix across the C chunks.
// powf hoisted: (1-s)^L once per thread; only a ragged final chunk pays
// a second powf. (R2's 400 powf/thread cost 120 us.)
// ---------------------------------------------------------------------------
__global__ void pcen_chunk_prefix(const float4* __restrict__ contrib,
                                  const float* __restrict__ log_s,
                                  float4* __restrict__ m_start,
                                  int B, int T, int Q, int C, int L) {
    int tid = blockIdx.x * blockDim.x + threadIdx.x;
    if (tid >= B * Q) return;
    int q = tid % Q;
    int b = tid / Q;

    float sx = expf(log_s[q * 4 + 0]);
    float sy = expf(log_s[q * 4 + 1]);
    float sz = expf(log_s[q * 4 + 2]);
    float sw = expf(log_s[q * 4 + 3]);
    float ox = 1.0f - sx, oy = 1.0f - sy, oz = 1.0f - sz, ow = 1.0f - sw;

    // full-chunk decay factors, computed once
    float gx = powf(ox, (float)L);
    float gy = powf(oy, (float)L);
    float gz = powf(oz, (float)L);
    float gw = powf(ow, (float)L);

    float mx = 0.f, my = 0.f, mz = 0.f, mw = 0.f;
    int base = b * C * Q + q;
    for (int c = 0; c < C; ++c) {
        m_start[base + c * Q] = make_float4(mx, my, mz, mw);
        int start = c * L;
        int len = T - start;
        if (len > L) len = L;
        if (len < 0) len = 0;
        float fx, fy, fz, fw;
        if (len == L) {
            fx = gx; fy = gy; fz = gz; fw = gw;
        } else {  // ragged final chunk only
            fx = powf(ox, (float)len);
            fy = powf(oy, (float)len);
            fz = powf(oz, (float)len);
            fw = powf(ow, (float)len);
        }
        float4 cv = contrib[base + c * Q];
        mx = fmaf(fx, mx, cv.x);
        my = fmaf(fy, my, cv.y);
        mz = fmaf(fz, mz, cv.z);
        mw = fmaf(fw, mw, cv.w);
    }
}

// ---------------------------------------------------------------------------
// K3: per-(b, chunk, q) re-scan with correct start state + PCEN epilogue.
// out = (x * (m+eps)^-alpha + delta)^r - delta^r
// ---------------------------------------------------------------------------
__device__ __forceinline__ float pcen_out(float xv, float m, float alpha,
                                          float delta, float r, float delta_r) {
    float p = __expf(-alpha * __logf(m + PCEN_EPS));
    float y = fmaf(xv, p, delta);
    return __expf(r * __logf(y)) - delta_r;
}

__global__ void pcen_output(const float4* __restrict__ x,
                            const float* __restrict__ log_s,
                            const float* __restrict__ log_alpha,
                            const float* __restrict__ log_delta,
                            const float* __restrict__ log_r,
                            const float4* __restrict__ m_start,
                            float4* __restrict__ out,
                            int B, int T, int Q, int C, int L) {
    int tid = blockIdx.x * blockDim.x + threadIdx.x;
    int total = B * C * Q;
    if (tid >= total) return;
    int q = tid % Q;
    int c = (tid / Q) % C;
    int b = tid / (Q * C);

    float sx = expf(log_s[q * 4 + 0]);
    float sy = expf(log_s[q * 4 + 1]);
    float sz = expf(log_s[q * 4 + 2]);
    float sw = expf(log_s[q * 4 + 3]);
    float ox = 1.0f - sx, oy = 1.0f - sy, oz = 1.0f - sz, ow = 1.0f - sw;

    float ax = expf(log_alpha[q * 4 + 0]);
    float ay = expf(log_alpha[q * 4 + 1]);
    float az = expf(log_alpha[q * 4 + 2]);
    float aw = expf(log_alpha[q * 4 + 3]);

    float dx = expf(log_delta[q * 4 + 0]);
    float dy = expf(log_delta[q * 4 + 1]);
    float dz = expf(log_delta[q * 4 + 2]);
    float dw = expf(log_delta[q * 4 + 3]);

    float rx = expf(log_r[q * 4 + 0]);
    float ry = expf(log_r[q * 4 + 1]);
    float rz = expf(log_r[q * 4 + 2]);
    float rw = expf(log_r[q * 4 + 3]);

    float drx = powf(dx, rx), dry = powf(dy, ry);
    float drz = powf(dz, rz), drw = powf(dw, rw);

    int start = c * L;
    int len = T - start;
    if (len > L) len = L;
    if (len < 0) len = 0;

    float4 m0 = m_start[tid];
    float mx = m0.x, my = m0.y, mz = m0.z, mw = m0.w;

    long base = (long)(b * (long)T + start) * Q + q;
#pragma unroll 8
    for (int i = 0; i < len; ++i) {
        float4 xv = x[base];
        mx = fmaf(ox, mx, sx * xv.x);
        my = fmaf(oy, my, sy * xv.y);
        mz = fmaf(oz, mz, sz * xv.z);
        mw = fmaf(ow, mw, sw * xv.w);
        vfloat4 ov;
        ov.x = pcen_out(xv.x, mx, ax, dx, rx, drx);
        ov.y = pcen_out(xv.y, my, ay, dy, ry, dry);
        ov.z = pcen_out(xv.z, mz, az, dz, rz, drz);
        ov.w = pcen_out(xv.w, mw, aw, dw, rw, drw);
        // out is never re-read: non-temporal store keeps L2/L3 for x reuse.
        // Cast to native vector type for the builtin.
        __builtin_nontemporal_store(ov, (vfloat4*)&out[base]);
        base += Q;
    }
}

extern "C" void kernel_launch(void* const* d_in, const int* in_sizes, int n_in,
                              void* d_out, int out_size, void* d_ws, size_t ws_size,
                              hipStream_t stream) {
    const float4* x        = (const float4*)d_in[0];
    const float* log_s     = (const float*)d_in[1];
    const float* log_alpha = (const float*)d_in[2];
    const float* log_delta = (const float*)d_in[3];
    const float* log_r     = (const float*)d_in[4];
    float4* out = (float4*)d_out;

    const int M = in_sizes[1];            // 80
    const int Q = M / 4;                  // 20 float4s per row
    const int B = 64;                     // per reference setup
    const int T = in_sizes[0] / (B * M);  // 8000

    // Chunk count C: parallelism = B*C*Q threads; workspace = 2*B*C*M floats.
    // C=200 -> L=40, 256K threads, 1000 blocks (4 blocks/CU, 16 waves/CU).
    int C = 200;
    while (C > 1 && (size_t)(2ll * B * C * M * 4) > ws_size) C--;
    const int L = (T + C - 1) / C;

    float4* contrib = (float4*)d_ws;                       // B*C*Q float4s
    float4* mstart  = contrib + (size_t)B * C * Q;         // B*C*Q float4s

    const int threads = 256;
    int total1 = B * C * Q;
    int total2 = B * Q;

    pcen_chunk_scan<<<(total1 + threads - 1) / threads, threads, 0, stream>>>(
        x, log_s, contrib, B, T, Q, C, L);
    pcen_chunk_prefix<<<(total2 + threads - 1) / threads, threads, 0, stream>>>(
        contrib, log_s, mstart, B, T, Q, C, L);
    pcen_output<<<(total1 + threads - 1) / threads, threads, 0, stream>>>(
        x, log_s, log_alpha, log_delta, log_r, mstart, out, B, T, Q, C, L);
}